// Round 11
// baseline (1074.069 us; speedup 1.0000x reference)
//
#include <hip/hip_runtime.h>

#define NUM_CLASSES 80
#define N13 507
#define N26 2028
#define N52 8112
#define NANCH (N13 + N26 + N52)   // 10647
#define BATCH 64
#define MAXB 100
#define NB 3720                    // float-bit buckets: (bits>>14) - 0xFC00, scores in (0.5, 79)
#define BOFF 0xFC00u
#define KPT 11                     // ceil(NANCH/1024)
#define TOPK 1024                  // region target size (scan needs ~456 for 100 accepts)
#define LCAP 4096                  // LDS ring capacity (power of 2)
#define LMASK (LCAP-1)
#define APB 64                     // anchors per 256-thread block (4 lanes/anchor)
#define REPEAT 32                  // probe amplification

typedef unsigned long long u64;

// ---------------- Phase 1: score = p * (float)argmax(classes), 4 lanes per anchor -------------
__global__ __launch_bounds__(256) void score_kernel(
    const float* __restrict__ c13, const float* __restrict__ p13,
    const float* __restrict__ c26, const float* __restrict__ p26,
    const float* __restrict__ c52, const float* __restrict__ p52,
    float* __restrict__ scores)
{
    int a   = blockIdx.x * APB + (threadIdx.x >> 2);
    int sub = threadIdx.x & 3;
    int b   = blockIdx.y;
    if (a >= NANCH) return;
    const float* cbase; const float* pbase;
    if (a < N13)            { cbase = c13 + ((size_t)b*N13 + a) * NUM_CLASSES;           pbase = p13 + (size_t)b*N13 + a; }
    else if (a < N13+N26)   { cbase = c26 + ((size_t)b*N26 + (a-N13)) * NUM_CLASSES;     pbase = p26 + (size_t)b*N26 + (a-N13); }
    else                    { cbase = c52 + ((size_t)b*N52 + (a-N13-N26)) * NUM_CLASSES; pbase = p52 + (size_t)b*N52 + (a-N13-N26); }
    float mx = -1.0f; int mi = 0;
    #pragma unroll
    for (int q = 0; q < 5; ++q) {
        float4 v = *(const float4*)(cbase + q*16 + sub*4);
        int cb = q*16 + sub*4;
        if (v.x > mx) { mx = v.x; mi = cb+0; }   // strict > keeps FIRST max
        if (v.y > mx) { mx = v.y; mi = cb+1; }
        if (v.z > mx) { mx = v.z; mi = cb+2; }
        if (v.w > mx) { mx = v.w; mi = cb+3; }
    }
    #pragma unroll
    for (int off = 1; off < 4; off <<= 1) {
        float ov = __shfl_xor(mx, off);
        int   oi = __shfl_xor(mi, off);
        if (ov > mx || (ov == mx && oi < mi)) { mx = ov; mi = oi; }
    }
    if (sub == 0) scores[(size_t)b*NANCH + a] = pbase[0] * (float)mi;
}

__device__ __forceinline__ float4 load_box(const float* __restrict__ b13,
                                           const float* __restrict__ b26,
                                           const float* __restrict__ b52,
                                           int b, int n)
{
    if (n < N13)          return *(const float4*)(b13 + ((size_t)b*N13 + n)*4);
    else if (n < N13+N26) return *(const float4*)(b26 + ((size_t)b*N26 + (n-N13))*4);
    else                  return *(const float4*)(b52 + ((size_t)b*N52 + (n-N13-N26))*4);
}

// ---------------- Phase 2: top-K counting-sort + wave-parallel scan NMS (R10 verbatim) --------
__global__ __launch_bounds__(1024) void nms_sort_scan(
    const float* __restrict__ scores,
    const float* __restrict__ b13, const float* __restrict__ b26, const float* __restrict__ b52,
    float* __restrict__ out)
{
    const int b    = blockIdx.x;
    const int tid  = threadIdx.x;
    const int lane = tid & 63;
    const int wid  = tid >> 6;

    __shared__ u64 lst[LCAP];
    __shared__ unsigned int cnt[NB];
    __shared__ unsigned int wtot[16];
    __shared__ float4 acc4[MAXB];
    __shared__ u64 sup_lds[16];
    __shared__ float outrec[MAXB][6];
    __shared__ int accN_s, T_s, L_s;

    const float* sc = scores + (size_t)b * NANCH;

    float sreg[KPT];
    #pragma unroll
    for (int k = 0; k < KPT; ++k) {
        int n = tid + (k << 10);
        sreg[k] = (n < NANCH) ? sc[n] : 0.f;
    }

    for (int i = tid; i < NB; i += 1024) cnt[i] = 0u;
    if (tid == 0) accN_s = 0;
    __syncthreads();

    #pragma unroll
    for (int k = 0; k < KPT; ++k) {
        float s = sreg[k];
        if (s > 0.5f) {
            unsigned int bk = (__float_as_uint(s) >> 14) - BOFF;
            if (bk >= NB) bk = NB - 1;
            atomicAdd(&cnt[bk], 1u);
        }
    }
    __syncthreads();

    unsigned int loc[4]; unsigned int s4 = 0u;
    #pragma unroll
    for (int q = 0; q < 4; ++q) {
        int r = tid*4 + q;
        unsigned int v = (r < NB) ? cnt[NB-1-r] : 0u;
        loc[q] = v; s4 += v;
    }
    unsigned int incl = s4;
    #pragma unroll
    for (int off = 1; off < 64; off <<= 1) {
        unsigned int v = __shfl_up(incl, off);
        if (lane >= off) incl += v;
    }
    if (lane == 63) wtot[wid] = incl;
    __syncthreads();
    unsigned int wexcl = 0u, total = 0u;
    #pragma unroll
    for (int w = 0; w < 16; ++w) { unsigned int t = wtot[w]; if (w < wid) wexcl += t; total += t; }
    unsigned int run = wexcl + (incl - s4);
    if (tid == 0) { T_s = 0; L_s = (int)total; }
    __syncthreads();
    #pragma unroll
    for (int q = 0; q < 4; ++q) {
        int r = tid*4 + q;
        if (r < NB) {
            int bk = NB-1-r;
            unsigned int c = loc[q];
            if (run < TOPK && run + c >= TOPK) { T_s = bk; L_s = (int)(run + c); }
            cnt[bk] = run;
            run += c;
        }
    }
    __syncthreads();
    const int total_i = (int)total;
    int Treg = T_s;
    int regionEnd = L_s;

    #pragma unroll
    for (int k = 0; k < KPT; ++k) {
        float s = sreg[k];
        if (s > 0.5f) {
            unsigned int bits = __float_as_uint(s);
            unsigned int bk = (bits >> 14) - BOFF;
            if (bk >= NB) bk = NB - 1;
            if ((int)bk >= Treg) {
                unsigned int pos = atomicAdd(&cnt[bk], 1u);
                lst[pos & LMASK] = ((u64)bits << 32) | (u64)(0xFFFFFFFFu - (unsigned int)(tid + (k<<10)));
            }
        }
    }
    __syncthreads();

    {
        u64 kk[4]; int tt[4];
        #pragma unroll
        for (int i = 0; i < 4; ++i) {
            int p = tid + (i << 10);
            tt[i] = -1; kk[i] = 0ull;
            if (p < regionEnd) {
                u64 key = lst[p & LMASK];
                unsigned int bk = (unsigned int)(key >> 46) - BOFF;
                if (bk >= NB) bk = NB - 1;
                unsigned int st = (bk+1 < NB) ? cnt[bk+1] : 0u;
                unsigned int e  = cnt[bk];
                unsigned int rank = 0u;
                for (unsigned int q = st; q < e; ++q) rank += (lst[q & LMASK] > key) ? 1u : 0u;
                kk[i] = key; tt[i] = (int)(st + rank);
            }
        }
        __syncthreads();
        #pragma unroll
        for (int i = 0; i < 4; ++i) if (tt[i] >= 0) lst[tt[i] & LMASK] = kk[i];
        __syncthreads();
    }

    int accN = 0;
    u64 key = 0ull; float4 bb = make_float4(0.f,0.f,0.f,0.f); float s = 0.f;
    if (lane < regionEnd) {
        key = lst[lane];
        unsigned int n = 0xFFFFFFFFu - (unsigned int)(key & 0xFFFFFFFFull);
        s = __uint_as_float((unsigned int)(key >> 32));
        bb = load_box(b13, b26, b52, b, (int)n);
    }

    int c = 0;
    while (c < total_i && accN < MAXB) {
        while (c + 64 > regionEnd && regionEnd < total_i) {
            int K2 = regionEnd + TOPK;
            if (tid == 0) { T_s = 0; L_s = total_i; }
            __syncthreads();
            for (int bk = tid; bk < Treg; bk += 1024) {
                unsigned int stv = cnt[bk];
                unsigned int ev  = (bk == 0) ? (unsigned int)total_i : cnt[bk-1];
                if (stv < (unsigned int)K2 && ev >= (unsigned int)K2) { T_s = bk; L_s = (int)ev; }
            }
            __syncthreads();
            int T2 = T_s, L2 = L_s;
            #pragma unroll
            for (int k = 0; k < KPT; ++k) {
                float sv = sreg[k];
                if (sv > 0.5f) {
                    unsigned int bits = __float_as_uint(sv);
                    int bk = (int)((bits >> 14) - BOFF);
                    if (bk >= NB) bk = NB - 1;
                    if (bk >= T2 && bk < Treg) {
                        unsigned int pos = atomicAdd(&cnt[bk], 1u);
                        lst[pos & LMASK] = ((u64)bits << 32) | (u64)(0xFFFFFFFFu - (unsigned int)(tid + (k<<10)));
                    }
                }
            }
            __syncthreads();
            {
                u64 kk[4]; int tt[4];
                #pragma unroll
                for (int i = 0; i < 4; ++i) {
                    int p = regionEnd + tid + (i << 10);
                    tt[i] = -1; kk[i] = 0ull;
                    if (p < L2) {
                        u64 k2 = lst[p & LMASK];
                        unsigned int bk = (unsigned int)(k2 >> 46) - BOFF;
                        if (bk >= NB) bk = NB - 1;
                        unsigned int st = (bk+1 < NB) ? cnt[bk+1] : 0u;
                        unsigned int e  = cnt[bk];
                        unsigned int rank = 0u;
                        for (unsigned int q = st; q < e; ++q) rank += (lst[q & LMASK] > k2) ? 1u : 0u;
                        kk[i] = k2; tt[i] = (int)(st + rank);
                    }
                }
                __syncthreads();
                #pragma unroll
                for (int i = 0; i < 4; ++i) if (tt[i] >= 0) lst[tt[i] & LMASK] = kk[i];
                __syncthreads();
            }
            Treg = T2; regionEnd = L2;
            key = 0ull; bb = make_float4(0.f,0.f,0.f,0.f); s = 0.f;
            if (c + lane < regionEnd) {
                key = lst[(c + lane) & LMASK];
                unsigned int n = 0xFFFFFFFFu - (unsigned int)(key & 0xFFFFFFFFull);
                s = __uint_as_float((unsigned int)(key >> 32));
                bb = load_box(b13, b26, b52, b, (int)n);
            }
        }

        int m = regionEnd - c; if (m > 64) m = 64;
        float oy1 = bb.x, ox1 = bb.y, oy2 = bb.z, ox2 = bb.w, cs = s;
        float y1 = fminf(oy1, oy2), y2 = fmaxf(oy1, oy2);
        float x1 = fminf(ox1, ox2), x2 = fmaxf(ox1, ox2);
        float ar = (y2-y1)*(x2-x1);

        int nc = c + 64;
        if (nc + lane < regionEnd) {
            key = lst[(nc + lane) & LMASK];
            unsigned int n = 0xFFFFFFFFu - (unsigned int)(key & 0xFFFFFFFFull);
            s = __uint_as_float((unsigned int)(key >> 32));
            bb = load_box(b13, b26, b52, b, (int)n);
        } else { s = 0.f; bb = make_float4(0.f,0.f,0.f,0.f); }

        bool supp = (lane >= m);
        #pragma unroll 2
        for (int j = wid; j < accN; j += 16) {
            float4 aj = acc4[j];
            float jar = (aj.z - aj.x) * (aj.w - aj.y);
            float iy1=fmaxf(y1,aj.x), iy2=fminf(y2,aj.z);
            float ix1=fmaxf(x1,aj.y), ix2=fminf(x2,aj.w);
            float inter=fmaxf(iy2-iy1,0.f)*fmaxf(ix2-ix1,0.f);
            float un=(ar+jar)-inter;
            supp |= (un > 0.f) && (inter/un > 0.5f);
        }
        u64 bal = __ballot(supp);
        if (lane == 0) sup_lds[wid] = bal;
        __syncthreads();

        if (wid == 0) {
            u64 B = 0ull;
            #pragma unroll
            for (int w = 0; w < 16; ++w) B |= sup_lds[w];
            u64 valid_m = (m >= 64) ? ~0ull : ((1ull << m) - 1ull);
            u64 rem = (~B) & valid_m;
            while (rem && accN < MAXB) {
                int j = __builtin_ctzll(rem);
                float jy1=__shfl(y1,j), jx1=__shfl(x1,j), jy2=__shfl(y2,j);
                float jx2=__shfl(x2,j), jar=__shfl(ar,j);
                if (lane == j) {
                    acc4[accN] = make_float4(y1, x1, y2, x2);
                    outrec[accN][0]=fminf(fmaxf(oy1,0.f),1.f);
                    outrec[accN][1]=fminf(fmaxf(ox1,0.f),1.f);
                    outrec[accN][2]=fminf(fmaxf(oy2,0.f),1.f);
                    outrec[accN][3]=fminf(fmaxf(ox2,0.f),1.f);
                    outrec[accN][4]=cs;
                    outrec[accN][5]=0.f;
                }
                float iy1=fmaxf(y1,jy1), iy2=fminf(y2,jy2);
                float ix1=fmaxf(x1,jx1), ix2=fminf(x2,jx2);
                float inter=fmaxf(iy2-iy1,0.f)*fmaxf(ix2-ix1,0.f);
                float un=(ar+jar)-inter;
                bool kill = (un > 0.f) && (inter/un > 0.5f);
                rem &= ~__ballot(kill);
                rem &= ~(1ull << j);
                accN++;
            }
            if (lane == 0) accN_s = accN;
        }
        __syncthreads();
        accN = accN_s;
        c += 64;
    }

    const int accNf = accN_s;
    float* outp = out + (size_t)b * (MAXB*6);
    for (int i = tid; i < MAXB*6; i += 1024) {
        int t = i / 6;
        outp[i] = (t < accNf) ? outrec[t][i % 6] : 0.f;
    }
    if (tid == 0) out[(size_t)BATCH*(MAXB*6) + b] = (float)accNf;
}

// ---------------- DIAGNOSTIC PROBES: repeat one nms phase REPEAT× so it tops rocprof ----------
// PHASE 1: hist only. PHASE 2: full preamble. PHASE 3: preamble once + REPEAT× scan.
template<int PHASE>
__global__ __launch_bounds__(1024) void nms_probe(
    const float* __restrict__ scores,
    const float* __restrict__ b13, const float* __restrict__ b26, const float* __restrict__ b52,
    float* __restrict__ dump)
{
    const int b    = blockIdx.x;
    const int tid  = threadIdx.x;
    const int lane = tid & 63;
    const int wid  = tid >> 6;

    __shared__ u64 lst[LCAP];
    __shared__ unsigned int cnt[NB];
    __shared__ unsigned int wtot[16];
    __shared__ float4 acc4[MAXB];
    __shared__ u64 sup_lds[16];
    __shared__ float outrec[MAXB][6];
    __shared__ int accN_s, T_s, L_s;

    const float* sc = scores + (size_t)b * NANCH;
    float sreg[KPT];
    #pragma unroll
    for (int k = 0; k < KPT; ++k) {
        int n = tid + (k << 10);
        sreg[k] = (n < NANCH) ? sc[n] : 0.f;
    }

    int Treg = 0, regionEnd = 0, total_i = 0;

    const int PRE_ITERS = (PHASE == 3) ? 1 : REPEAT;
    for (int it = 0; it < PRE_ITERS; ++it) {
        // zero + hist
        for (int i = tid; i < NB; i += 1024) cnt[i] = 0u;
        if (tid == 0) accN_s = 0;
        __syncthreads();
        #pragma unroll
        for (int k = 0; k < KPT; ++k) {
            float s = sreg[k];
            if (s > 0.5f) {
                unsigned int bk = (__float_as_uint(s) >> 14) - BOFF;
                if (bk >= NB) bk = NB - 1;
                atomicAdd(&cnt[bk], 1u);
            }
        }
        __syncthreads();
        if (PHASE == 1) continue;

        // prefix
        unsigned int loc[4]; unsigned int s4 = 0u;
        #pragma unroll
        for (int q = 0; q < 4; ++q) {
            int r = tid*4 + q;
            unsigned int v = (r < NB) ? cnt[NB-1-r] : 0u;
            loc[q] = v; s4 += v;
        }
        unsigned int incl = s4;
        #pragma unroll
        for (int off = 1; off < 64; off <<= 1) {
            unsigned int v = __shfl_up(incl, off);
            if (lane >= off) incl += v;
        }
        if (lane == 63) wtot[wid] = incl;
        __syncthreads();
        unsigned int wexcl = 0u, total = 0u;
        #pragma unroll
        for (int w = 0; w < 16; ++w) { unsigned int t = wtot[w]; if (w < wid) wexcl += t; total += t; }
        unsigned int run = wexcl + (incl - s4);
        if (tid == 0) { T_s = 0; L_s = (int)total; }
        __syncthreads();
        #pragma unroll
        for (int q = 0; q < 4; ++q) {
            int r = tid*4 + q;
            if (r < NB) {
                int bk = NB-1-r;
                unsigned int c = loc[q];
                if (run < TOPK && run + c >= TOPK) { T_s = bk; L_s = (int)(run + c); }
                cnt[bk] = run;
                run += c;
            }
        }
        __syncthreads();
        total_i = (int)total;
        Treg = T_s;
        regionEnd = L_s;

        // scatter
        #pragma unroll
        for (int k = 0; k < KPT; ++k) {
            float s = sreg[k];
            if (s > 0.5f) {
                unsigned int bits = __float_as_uint(s);
                unsigned int bk = (bits >> 14) - BOFF;
                if (bk >= NB) bk = NB - 1;
                if ((int)bk >= Treg) {
                    unsigned int pos = atomicAdd(&cnt[bk], 1u);
                    lst[pos & LMASK] = ((u64)bits << 32) | (u64)(0xFFFFFFFFu - (unsigned int)(tid + (k<<10)));
                }
            }
        }
        __syncthreads();

        // rank-permute
        u64 kk[4]; int tt[4];
        #pragma unroll
        for (int i = 0; i < 4; ++i) {
            int p = tid + (i << 10);
            tt[i] = -1; kk[i] = 0ull;
            if (p < regionEnd) {
                u64 key = lst[p & LMASK];
                unsigned int bk = (unsigned int)(key >> 46) - BOFF;
                if (bk >= NB) bk = NB - 1;
                unsigned int st = (bk+1 < NB) ? cnt[bk+1] : 0u;
                unsigned int e  = cnt[bk];
                unsigned int rank = 0u;
                for (unsigned int q = st; q < e; ++q) rank += (lst[q & LMASK] > key) ? 1u : 0u;
                kk[i] = key; tt[i] = (int)(st + rank);
            }
        }
        __syncthreads();
        #pragma unroll
        for (int i = 0; i < 4; ++i) if (tt[i] >= 0) lst[tt[i] & LMASK] = kk[i];
        __syncthreads();
    }

    int accN = 0;
    if (PHASE == 3) {
        for (int it = 0; it < REPEAT; ++it) {
            if (tid == 0) accN_s = 0;
            __syncthreads();
            accN = 0;
            u64 key = 0ull; float4 bb = make_float4(0.f,0.f,0.f,0.f); float s = 0.f;
            if (lane < regionEnd) {
                key = lst[lane];
                unsigned int n = 0xFFFFFFFFu - (unsigned int)(key & 0xFFFFFFFFull);
                s = __uint_as_float((unsigned int)(key >> 32));
                bb = load_box(b13, b26, b52, b, (int)n);
            }
            int c = 0;
            while (c < total_i && accN < MAXB) {
                if (c + 64 > regionEnd && regionEnd < total_i) break;   // extension elided in probe
                int m = regionEnd - c; if (m > 64) m = 64;
                float oy1 = bb.x, ox1 = bb.y, oy2 = bb.z, ox2 = bb.w, cs = s;
                float y1 = fminf(oy1, oy2), y2 = fmaxf(oy1, oy2);
                float x1 = fminf(ox1, ox2), x2 = fmaxf(ox1, ox2);
                float ar = (y2-y1)*(x2-x1);
                int nc = c + 64;
                if (nc + lane < regionEnd) {
                    key = lst[(nc + lane) & LMASK];
                    unsigned int n = 0xFFFFFFFFu - (unsigned int)(key & 0xFFFFFFFFull);
                    s = __uint_as_float((unsigned int)(key >> 32));
                    bb = load_box(b13, b26, b52, b, (int)n);
                } else { s = 0.f; bb = make_float4(0.f,0.f,0.f,0.f); }

                bool supp = (lane >= m);
                #pragma unroll 2
                for (int j = wid; j < accN; j += 16) {
                    float4 aj = acc4[j];
                    float jar = (aj.z - aj.x) * (aj.w - aj.y);
                    float iy1=fmaxf(y1,aj.x), iy2=fminf(y2,aj.z);
                    float ix1=fmaxf(x1,aj.y), ix2=fminf(x2,aj.w);
                    float inter=fmaxf(iy2-iy1,0.f)*fmaxf(ix2-ix1,0.f);
                    float un=(ar+jar)-inter;
                    supp |= (un > 0.f) && (inter/un > 0.5f);
                }
                u64 bal = __ballot(supp);
                if (lane == 0) sup_lds[wid] = bal;
                __syncthreads();
                if (wid == 0) {
                    u64 B = 0ull;
                    #pragma unroll
                    for (int w = 0; w < 16; ++w) B |= sup_lds[w];
                    u64 valid_m = (m >= 64) ? ~0ull : ((1ull << m) - 1ull);
                    u64 rem = (~B) & valid_m;
                    while (rem && accN < MAXB) {
                        int j = __builtin_ctzll(rem);
                        float jy1=__shfl(y1,j), jx1=__shfl(x1,j), jy2=__shfl(y2,j);
                        float jx2=__shfl(x2,j), jar=__shfl(ar,j);
                        if (lane == j) {
                            acc4[accN] = make_float4(y1, x1, y2, x2);
                            outrec[accN][0]=fminf(fmaxf(oy1,0.f),1.f);
                            outrec[accN][1]=fminf(fmaxf(ox1,0.f),1.f);
                            outrec[accN][2]=fminf(fmaxf(oy2,0.f),1.f);
                            outrec[accN][3]=fminf(fmaxf(ox2,0.f),1.f);
                            outrec[accN][4]=cs;
                            outrec[accN][5]=0.f;
                        }
                        float iy1=fmaxf(y1,jy1), iy2=fminf(y2,jy2);
                        float ix1=fmaxf(x1,jx1), ix2=fminf(x2,jx2);
                        float inter=fmaxf(iy2-iy1,0.f)*fmaxf(ix2-ix1,0.f);
                        float un=(ar+jar)-inter;
                        bool kill = (un > 0.f) && (inter/un > 0.5f);
                        rem &= ~__ballot(kill);
                        rem &= ~(1ull << j);
                        accN++;
                    }
                    if (lane == 0) accN_s = accN;
                }
                __syncthreads();
                accN = accN_s;
                c += 64;
            }
            __syncthreads();
        }
    }

    // keep everything live; deterministic scratch write
    __syncthreads();
    float v = (float)cnt[(tid * 3) % NB] + (float)accN;
    if (PHASE >= 2) v += (float)(unsigned int)(lst[tid & LMASK] & 0xFFFFu);
    if (PHASE == 3) v += outrec[tid % MAXB][tid % 6];
    dump[(size_t)b * 1024 + tid] = v;
}

extern "C" void kernel_launch(void* const* d_in, const int* in_sizes, int n_in,
                              void* d_out, int out_size, void* d_ws, size_t ws_size,
                              hipStream_t stream)
{
    const float* bbox13 = (const float*)d_in[0];
    const float* p13    = (const float*)d_in[1];
    const float* c13    = (const float*)d_in[2];
    const float* bbox26 = (const float*)d_in[3];
    const float* p26    = (const float*)d_in[4];
    const float* c26    = (const float*)d_in[5];
    const float* bbox52 = (const float*)d_in[6];
    const float* p52    = (const float*)d_in[7];
    const float* c52    = (const float*)d_in[8];
    float* out    = (float*)d_out;
    char*  ws     = (char*)d_ws;
    float* scores = (float*)ws;                      // 2.7 MB
    float* dump1  = (float*)(ws + (16u<<20));
    float* dump2  = (float*)(ws + (20u<<20));
    float* dump3  = (float*)(ws + (24u<<20));

    dim3 g1((NANCH + APB - 1)/APB, BATCH);
    score_kernel<<<g1, 256, 0, stream>>>(c13, p13, c26, p26, c52, p52, scores);
    nms_sort_scan<<<BATCH, 1024, 0, stream>>>(scores, bbox13, bbox26, bbox52, out);
    // diagnostics (results unused; durations + counters read via rocprof top-5)
    nms_probe<1><<<BATCH, 1024, 0, stream>>>(scores, bbox13, bbox26, bbox52, dump1);
    nms_probe<2><<<BATCH, 1024, 0, stream>>>(scores, bbox13, bbox26, bbox52, dump2);
    nms_probe<3><<<BATCH, 1024, 0, stream>>>(scores, bbox13, bbox26, bbox52, dump3);
}

// Round 12
// 69.952 us; speedup vs baseline: 15.3545x; 15.3545x over previous
//
#include <hip/hip_runtime.h>

#define NUM_CLASSES 80
#define N13 507
#define N26 2028
#define N52 8112
#define NANCH (N13 + N26 + N52)   // 10647
#define BATCH 64
#define MAXB 100
#define NB 3720                    // float-bit buckets: (bits>>14) - 0xFC00, scores in (0.5, 79)
#define BOFF 0xFC00u
#define KPT 11                     // ceil(NANCH/1024)
#define TOPK 1024                  // region target size (scan needs ~456 for 100 accepts)
#define LCAP 4096                  // LDS ring capacity (power of 2)
#define LMASK (LCAP-1)
#define APB 64                     // anchors per 256-thread block (4 lanes/anchor)

typedef unsigned long long u64;

// ---------------- Phase 1: score = p * (float)argmax(classes), 4 lanes per anchor -------------
__global__ __launch_bounds__(256) void score_kernel(
    const float* __restrict__ c13, const float* __restrict__ p13,
    const float* __restrict__ c26, const float* __restrict__ p26,
    const float* __restrict__ c52, const float* __restrict__ p52,
    float* __restrict__ scores)
{
    int a   = blockIdx.x * APB + (threadIdx.x >> 2);
    int sub = threadIdx.x & 3;
    int b   = blockIdx.y;
    if (a >= NANCH) return;
    const float* cbase; const float* pbase;
    if (a < N13)            { cbase = c13 + ((size_t)b*N13 + a) * NUM_CLASSES;           pbase = p13 + (size_t)b*N13 + a; }
    else if (a < N13+N26)   { cbase = c26 + ((size_t)b*N26 + (a-N13)) * NUM_CLASSES;     pbase = p26 + (size_t)b*N26 + (a-N13); }
    else                    { cbase = c52 + ((size_t)b*N52 + (a-N13-N26)) * NUM_CLASSES; pbase = p52 + (size_t)b*N52 + (a-N13-N26); }
    float mx = -1.0f; int mi = 0;
    #pragma unroll
    for (int q = 0; q < 5; ++q) {
        float4 v = *(const float4*)(cbase + q*16 + sub*4);
        int cb = q*16 + sub*4;
        if (v.x > mx) { mx = v.x; mi = cb+0; }   // strict > keeps FIRST max
        if (v.y > mx) { mx = v.y; mi = cb+1; }
        if (v.z > mx) { mx = v.z; mi = cb+2; }
        if (v.w > mx) { mx = v.w; mi = cb+3; }
    }
    #pragma unroll
    for (int off = 1; off < 4; off <<= 1) {
        float ov = __shfl_xor(mx, off);
        int   oi = __shfl_xor(mi, off);
        if (ov > mx || (ov == mx && oi < mi)) { mx = ov; mi = oi; }
    }
    if (sub == 0) scores[(size_t)b*NANCH + a] = pbase[0] * (float)mi;
}

__device__ __forceinline__ float4 load_box(const float* __restrict__ b13,
                                           const float* __restrict__ b26,
                                           const float* __restrict__ b52,
                                           int b, int n)
{
    if (n < N13)          return *(const float4*)(b13 + ((size_t)b*N13 + n)*4);
    else if (n < N13+N26) return *(const float4*)(b26 + ((size_t)b*N26 + (n-N13))*4);
    else                  return *(const float4*)(b52 + ((size_t)b*N52 + (n-N13-N26))*4);
}

// ---------------- Phase 2: top-K counting-sort + wave-parallel scan NMS ----------------
// greedy argmax-NMS == scan in (score desc, idx asc) order, accept iff IoU<=0.5 vs all accepted.
__global__ __launch_bounds__(1024) void nms_sort_scan(
    const float* __restrict__ scores,
    const float* __restrict__ b13, const float* __restrict__ b26, const float* __restrict__ b52,
    float* __restrict__ out)
{
    const int b    = blockIdx.x;
    const int tid  = threadIdx.x;
    const int lane = tid & 63;
    const int wid  = tid >> 6;

    __shared__ u64 lst[LCAP];                   // 32 KB ring of sorted candidates
    __shared__ unsigned int cnt[NB];            // 14.9 KB
    __shared__ unsigned int wtot[16];
    __shared__ float4 acc4[MAXB];               // accepted canonical boxes (y1,x1,y2,x2)
    __shared__ float4 cbb[64];                  // current chunk canonical boxes
    __shared__ u64 sup_lds[16];
    __shared__ float outrec[MAXB][6];
    __shared__ int accN_s, T_s, L_s;

    const float* sc = scores + (size_t)b * NANCH;

    float sreg[KPT];
    #pragma unroll
    for (int k = 0; k < KPT; ++k) {
        int n = tid + (k << 10);
        sreg[k] = (n < NANCH) ? sc[n] : 0.f;
    }

    for (int i = tid; i < NB; i += 1024) cnt[i] = 0u;
    if (tid == 0) accN_s = 0;
    __syncthreads();

    #pragma unroll
    for (int k = 0; k < KPT; ++k) {
        float s = sreg[k];
        if (s > 0.5f) {
            unsigned int bk = (__float_as_uint(s) >> 14) - BOFF;
            if (bk >= NB) bk = NB - 1;
            atomicAdd(&cnt[bk], 1u);
        }
    }
    __syncthreads();

    unsigned int loc[4]; unsigned int s4 = 0u;
    #pragma unroll
    for (int q = 0; q < 4; ++q) {
        int r = tid*4 + q;
        unsigned int v = (r < NB) ? cnt[NB-1-r] : 0u;
        loc[q] = v; s4 += v;
    }
    unsigned int incl = s4;
    #pragma unroll
    for (int off = 1; off < 64; off <<= 1) {
        unsigned int v = __shfl_up(incl, off);
        if (lane >= off) incl += v;
    }
    if (lane == 63) wtot[wid] = incl;
    __syncthreads();
    unsigned int wexcl = 0u, total = 0u;
    #pragma unroll
    for (int w = 0; w < 16; ++w) { unsigned int t = wtot[w]; if (w < wid) wexcl += t; total += t; }
    unsigned int run = wexcl + (incl - s4);
    if (tid == 0) { T_s = 0; L_s = (int)total; }
    __syncthreads();
    #pragma unroll
    for (int q = 0; q < 4; ++q) {
        int r = tid*4 + q;
        if (r < NB) {
            int bk = NB-1-r;
            unsigned int c = loc[q];
            if (run < TOPK && run + c >= TOPK) { T_s = bk; L_s = (int)(run + c); }
            cnt[bk] = run;
            run += c;
        }
    }
    __syncthreads();
    const int total_i = (int)total;
    int Treg = T_s;
    int regionEnd = L_s;

    #pragma unroll
    for (int k = 0; k < KPT; ++k) {
        float s = sreg[k];
        if (s > 0.5f) {
            unsigned int bits = __float_as_uint(s);
            unsigned int bk = (bits >> 14) - BOFF;
            if (bk >= NB) bk = NB - 1;
            if ((int)bk >= Treg) {
                unsigned int pos = atomicAdd(&cnt[bk], 1u);
                lst[pos & LMASK] = ((u64)bits << 32) | (u64)(0xFFFFFFFFu - (unsigned int)(tid + (k<<10)));
            }
        }
    }
    __syncthreads();

    {
        u64 kk[4]; int tt[4];
        #pragma unroll
        for (int i = 0; i < 4; ++i) {
            int p = tid + (i << 10);
            tt[i] = -1; kk[i] = 0ull;
            if (p < regionEnd) {
                u64 key = lst[p & LMASK];
                unsigned int bk = (unsigned int)(key >> 46) - BOFF;
                if (bk >= NB) bk = NB - 1;
                unsigned int st = (bk+1 < NB) ? cnt[bk+1] : 0u;
                unsigned int e  = cnt[bk];
                unsigned int rank = 0u;
                for (unsigned int q = st; q < e; ++q) rank += (lst[q & LMASK] > key) ? 1u : 0u;
                kk[i] = key; tt[i] = (int)(st + rank);
            }
        }
        __syncthreads();
        #pragma unroll
        for (int i = 0; i < 4; ++i) if (tt[i] >= 0) lst[tt[i] & LMASK] = kk[i];
        __syncthreads();
    }

    // ---- wave-parallel chunked scan ----
    int accN = 0;
    u64 key = 0ull; float4 bb = make_float4(0.f,0.f,0.f,0.f); float s = 0.f;
    if (lane < regionEnd) {
        key = lst[lane];
        unsigned int n = 0xFFFFFFFFu - (unsigned int)(key & 0xFFFFFFFFull);
        s = __uint_as_float((unsigned int)(key >> 32));
        bb = load_box(b13, b26, b52, b, (int)n);
    }

    int c = 0;
    while (c < total_i && accN < MAXB) {
        // ---- region extension (fallback; never taken for bench data) ----
        while (c + 64 > regionEnd && regionEnd < total_i) {
            int K2 = regionEnd + TOPK;
            if (tid == 0) { T_s = 0; L_s = total_i; }
            __syncthreads();
            for (int bk = tid; bk < Treg; bk += 1024) {
                unsigned int stv = cnt[bk];
                unsigned int ev  = (bk == 0) ? (unsigned int)total_i : cnt[bk-1];
                if (stv < (unsigned int)K2 && ev >= (unsigned int)K2) { T_s = bk; L_s = (int)ev; }
            }
            __syncthreads();
            int T2 = T_s, L2 = L_s;
            #pragma unroll
            for (int k = 0; k < KPT; ++k) {
                float sv = sreg[k];
                if (sv > 0.5f) {
                    unsigned int bits = __float_as_uint(sv);
                    int bk = (int)((bits >> 14) - BOFF);
                    if (bk >= NB) bk = NB - 1;
                    if (bk >= T2 && bk < Treg) {
                        unsigned int pos = atomicAdd(&cnt[bk], 1u);
                        lst[pos & LMASK] = ((u64)bits << 32) | (u64)(0xFFFFFFFFu - (unsigned int)(tid + (k<<10)));
                    }
                }
            }
            __syncthreads();
            {
                u64 kk[4]; int tt[4];
                #pragma unroll
                for (int i = 0; i < 4; ++i) {
                    int p = regionEnd + tid + (i << 10);
                    tt[i] = -1; kk[i] = 0ull;
                    if (p < L2) {
                        u64 k2 = lst[p & LMASK];
                        unsigned int bk = (unsigned int)(k2 >> 46) - BOFF;
                        if (bk >= NB) bk = NB - 1;
                        unsigned int st = (bk+1 < NB) ? cnt[bk+1] : 0u;
                        unsigned int e  = cnt[bk];
                        unsigned int rank = 0u;
                        for (unsigned int q = st; q < e; ++q) rank += (lst[q & LMASK] > k2) ? 1u : 0u;
                        kk[i] = k2; tt[i] = (int)(st + rank);
                    }
                }
                __syncthreads();
                #pragma unroll
                for (int i = 0; i < 4; ++i) if (tt[i] >= 0) lst[tt[i] & LMASK] = kk[i];
                __syncthreads();
            }
            Treg = T2; regionEnd = L2;
            key = 0ull; bb = make_float4(0.f,0.f,0.f,0.f); s = 0.f;
            if (c + lane < regionEnd) {
                key = lst[(c + lane) & LMASK];
                unsigned int n = 0xFFFFFFFFu - (unsigned int)(key & 0xFFFFFFFFull);
                s = __uint_as_float((unsigned int)(key >> 32));
                bb = load_box(b13, b26, b52, b, (int)n);
            }
        }

        int m = regionEnd - c; if (m > 64) m = 64;
        float oy1 = bb.x, ox1 = bb.y, oy2 = bb.z, ox2 = bb.w, cs = s;
        float y1 = fminf(oy1, oy2), y2 = fmaxf(oy1, oy2);
        float x1 = fminf(ox1, ox2), x2 = fmaxf(ox1, ox2);
        float ar = (y2-y1)*(x2-x1);

        // prefetch next chunk
        int nc = c + 64;
        if (nc + lane < regionEnd) {
            key = lst[(nc + lane) & LMASK];
            unsigned int n = 0xFFFFFFFFu - (unsigned int)(key & 0xFFFFFFFFull);
            s = __uint_as_float((unsigned int)(key >> 32));
            bb = load_box(b13, b26, b52, b, (int)n);
        } else { s = 0.f; bb = make_float4(0.f,0.f,0.f,0.f); }

        // --- acc-check: wave w tests accepted slice {w, w+16, ...}; pipelined LDS reads ---
        bool supp = (lane >= m);
        #pragma unroll 2
        for (int j = wid; j < accN; j += 16) {
            float4 aj = acc4[j];                 // broadcast read, conflict-free
            float jar = (aj.z - aj.x) * (aj.w - aj.y);   // bit-identical to ref's area
            float iy1=fmaxf(y1,aj.x), iy2=fminf(y2,aj.z);
            float ix1=fmaxf(x1,aj.y), ix2=fminf(x2,aj.w);
            float inter=fmaxf(iy2-iy1,0.f)*fmaxf(ix2-ix1,0.f);
            float un=(ar+jar)-inter;
            supp |= (un > 0.f) && (inter/un > 0.5f);
        }
        u64 bal = __ballot(supp);
        if (lane == 0) sup_lds[wid] = bal;

        // --- wave 0: build per-lane kill-row (IoU symmetric => row == column) ---
        u64 myrow = 0ull;
        if (wid == 0) {
            cbb[lane] = make_float4(y1, x1, y2, x2);
            #pragma unroll 4
            for (int k = 0; k < m; ++k) {
                float4 ck = cbb[k];              // broadcast read, conflict-free
                float kar = (ck.z - ck.x) * (ck.w - ck.y);
                float iy1=fmaxf(y1,ck.x), iy2=fminf(y2,ck.z);
                float ix1=fmaxf(x1,ck.y), ix2=fminf(x2,ck.w);
                float inter=fmaxf(iy2-iy1,0.f)*fmaxf(ix2-ix1,0.f);
                float un=(ar+kar)-inter;
                if ((un > 0.f) && (inter/un > 0.5f)) myrow |= (1ull << k);
            }
        }
        __syncthreads();                         // sup_lds visible; acc4 reads done

        // --- wave 0: scalar resolve (readlane only — no shfl/ballot/IoU in the chain) ---
        if (wid == 0) {
            u64 B = 0ull;
            #pragma unroll
            for (int w = 0; w < 16; ++w) B |= sup_lds[w];
            u64 valid_m = (m >= 64) ? ~0ull : ((1ull << m) - 1ull);
            u64 rem = (~B) & valid_m;
            u64 accmask = 0ull;
            const int start = accN;
            while (rem && accN < MAXB) {
                int j = __builtin_ctzll(rem);
                u64 rowj = (u64)(unsigned int)__builtin_amdgcn_readlane((int)(myrow & 0xFFFFFFFFull), j)
                         | ((u64)(unsigned int)__builtin_amdgcn_readlane((int)(myrow >> 32), j) << 32);
                accmask |= (1ull << j);
                rem &= ~rowj;                    // row j includes bit j (self-IoU = 1)
                rem &= ~(1ull << j);
                accN++;
            }
            // parallel post-writes: accepted lanes write their own records in ctz order
            if (accmask & (1ull << lane)) {
                int pos = start + (int)__popcll(accmask & ((1ull << lane) - 1ull));
                acc4[pos] = make_float4(y1, x1, y2, x2);
                outrec[pos][0]=fminf(fmaxf(oy1,0.f),1.f);
                outrec[pos][1]=fminf(fmaxf(ox1,0.f),1.f);
                outrec[pos][2]=fminf(fmaxf(oy2,0.f),1.f);
                outrec[pos][3]=fminf(fmaxf(ox2,0.f),1.f);
                outrec[pos][4]=cs;
                outrec[pos][5]=0.f;
            }
            if (lane == 0) accN_s = accN;
        }
        __syncthreads();
        accN = accN_s;
        c += 64;
    }

    // ---- block-wide output write ----
    const int accNf = accN_s;
    float* outp = out + (size_t)b * (MAXB*6);
    for (int i = tid; i < MAXB*6; i += 1024) {
        int t = i / 6;
        outp[i] = (t < accNf) ? outrec[t][i % 6] : 0.f;
    }
    if (tid == 0) out[(size_t)BATCH*(MAXB*6) + b] = (float)accNf;
}

extern "C" void kernel_launch(void* const* d_in, const int* in_sizes, int n_in,
                              void* d_out, int out_size, void* d_ws, size_t ws_size,
                              hipStream_t stream)
{
    const float* bbox13 = (const float*)d_in[0];
    const float* p13    = (const float*)d_in[1];
    const float* c13    = (const float*)d_in[2];
    const float* bbox26 = (const float*)d_in[3];
    const float* p26    = (const float*)d_in[4];
    const float* c26    = (const float*)d_in[5];
    const float* bbox52 = (const float*)d_in[6];
    const float* p52    = (const float*)d_in[7];
    const float* c52    = (const float*)d_in[8];
    float* out    = (float*)d_out;
    float* scores = (float*)d_ws;   // 64*10647*4 = 2.7 MB

    dim3 g1((NANCH + APB - 1)/APB, BATCH);
    score_kernel<<<g1, 256, 0, stream>>>(c13, p13, c26, p26, c52, p52, scores);
    nms_sort_scan<<<BATCH, 1024, 0, stream>>>(scores, bbox13, bbox26, bbox52, out);
}